// Round 3
// baseline (210.445 us; speedup 1.0000x reference)
//
#include <hip/hip_runtime.h>
#include <hip/hip_bf16.h>

// Problem constants (from reference)
#define BATCH   16384
#define C_SEL   32
#define C_TOTAL 64
#define IN_F    128
#define OUT_F   128

#define BM      64    // batch rows per job
#define NGRP    32    // mtile groups (blocks per channel)
#define NJOBS   8     // jobs per block:  NGRP*NJOBS*BM == BATCH

typedef __bf16 bf16x8 __attribute__((ext_vector_type(8)));
typedef float  f32x4  __attribute__((ext_vector_type(4)));

__device__ __forceinline__ bf16x8 cvt_bf16x8(const float4 f0, const float4 f1) {
    bf16x8 a;
    a[0] = (__bf16)f0.x; a[1] = (__bf16)f0.y; a[2] = (__bf16)f0.z; a[3] = (__bf16)f0.w;
    a[4] = (__bf16)f1.x; a[5] = (__bf16)f1.y; a[6] = (__bf16)f1.z; a[7] = (__bf16)f1.w;
    return a;
}

__global__ __launch_bounds__(256, 4) void pl_mfma_kernel(
    const float* __restrict__ inp,       // (BATCH, C_SEL, IN_F)
    const float* __restrict__ weight,    // (C_TOTAL, OUT_F, IN_F)
    const float* __restrict__ bias,      // (C_TOTAL, OUT_F)
    const int*   __restrict__ channels,  // (C_SEL,)
    float*       __restrict__ out)       // (BATCH, C_SEL, OUT_F)
{
    // W[ch] as bf16 [128][128] = 32 KB; bank-conflict-free via 16B-unit XOR swizzle.
    __shared__ __bf16 ldsW[OUT_F * IN_F];

    const int bid = blockIdx.x;          // 1024 blocks
    const int c   = bid & 31;            // channel fastest
    const int g   = bid >> 5;            // mtile group 0..31
    const int ch  = channels[c];

    const int t  = threadIdx.x;
    const int w  = t >> 6;               // wave 0..3 -> rows [w*16, w*16+16)
    const int l  = t & 63;
    const int lr = l & 15;               // fragment row (A) / col (B)
    const int lg = l >> 4;               // k-group 0..3

    // ---- prefetch job 0 A (issue HBM loads first) ----
    float4 ra[8];                        // landing buffer: ks*2 + h
    {
        const size_t m = (size_t)g * BM + w * 16 + lr;   // job0 mtile = g
        const float* arow = inp + (m * C_SEL + (size_t)c) * IN_F;
        #pragma unroll
        for (int ks = 0; ks < 4; ++ks) {
            const float* p = arow + ks * 32 + lg * 8;
            ra[ks * 2]     = *reinterpret_cast<const float4*>(p);
            ra[ks * 2 + 1] = *reinterpret_cast<const float4*>(p + 4);
        }
    }

    // ---- stage W[ch] fp32 -> bf16 into LDS once (swizzled 16B units) ----
    const float* wsrc = weight + (size_t)ch * (OUT_F * IN_F);
    #pragma unroll
    for (int i = 0; i < 8; ++i) {
        const int fidx = i * 2048 + t * 8;
        const int row  = fidx >> 7;
        const int u    = (fidx & 127) >> 3;
        const float4 f0 = *reinterpret_cast<const float4*>(wsrc + fidx);
        const float4 f1 = *reinterpret_cast<const float4*>(wsrc + fidx + 4);
        const int up = u ^ (row & 7);
        *reinterpret_cast<bf16x8*>(&ldsW[row * IN_F + up * 8]) = cvt_bf16x8(f0, f1);
    }

    // ---- bias into registers (once) ----
    float bv[8];
    const float* brow = bias + (size_t)ch * OUT_F;
    #pragma unroll
    for (int nt = 0; nt < 8; ++nt) bv[nt] = brow[nt * 16 + lr];

    __syncthreads();

    // ---- job loop: convert -> prefetch next -> MFMA -> store ----
    for (int j = 0; j < NJOBS; ++j) {
        // convert landing buffer to MFMA fragments
        bf16x8 af[4];
        #pragma unroll
        for (int ks = 0; ks < 4; ++ks) af[ks] = cvt_bf16x8(ra[ks * 2], ra[ks * 2 + 1]);

        // issue next job's global loads (overlap with MFMA + stores below)
        if (j + 1 < NJOBS) {
            const size_t mn = ((size_t)(j + 1) * NGRP + g) * BM + w * 16 + lr;
            const float* arow = inp + (mn * C_SEL + (size_t)c) * IN_F;
            #pragma unroll
            for (int ks = 0; ks < 4; ++ks) {
                const float* p = arow + ks * 32 + lg * 8;
                ra[ks * 2]     = *reinterpret_cast<const float4*>(p);
                ra[ks * 2 + 1] = *reinterpret_cast<const float4*>(p + 4);
            }
        }

        // MFMA: out[m][o] = sum_k A[m][k] * W[o][k]
        f32x4 acc[8];
        #pragma unroll
        for (int nt = 0; nt < 8; ++nt) { f32x4 z = {0.f,0.f,0.f,0.f}; acc[nt] = z; }

        #pragma unroll
        for (int ks = 0; ks < 4; ++ks) {
            #pragma unroll
            for (int nt = 0; nt < 8; ++nt) {
                const int row = nt * 16 + lr;
                const int u   = (ks * 4 + lg) ^ (lr & 7);
                const bf16x8 b = *reinterpret_cast<const bf16x8*>(&ldsW[row * IN_F + u * 8]);
                acc[nt] = __builtin_amdgcn_mfma_f32_16x16x32_bf16(af[ks], b, acc[nt], 0, 0, 0);
            }
        }

        // epilogue: bias + nontemporal store (D: col = lr, row = lg*4 + j2)
        const size_t mtile = ((size_t)j * NGRP + g) * BM;
        #pragma unroll
        for (int j2 = 0; j2 < 4; ++j2) {
            const size_t m = mtile + w * 16 + lg * 4 + j2;
            float* orow = out + (m * C_SEL + (size_t)c) * OUT_F;
            #pragma unroll
            for (int nt = 0; nt < 8; ++nt) {
                __builtin_nontemporal_store(acc[nt][j2] + bv[nt], &orow[nt * 16 + lr]);
            }
        }
    }
}

extern "C" void kernel_launch(void* const* d_in, const int* in_sizes, int n_in,
                              void* d_out, int out_size, void* d_ws, size_t ws_size,
                              hipStream_t stream) {
    const float* inp      = (const float*)d_in[0];
    const float* weight   = (const float*)d_in[1];
    const float* bias     = (const float*)d_in[2];
    const int*   channels = (const int*)d_in[3];
    float*       out      = (float*)d_out;

    dim3 grid(C_SEL * NGRP);   // 1024 blocks, channel-fastest
    dim3 block(256);
    pl_mfma_kernel<<<grid, block, 0, stream>>>(inp, weight, bias, channels, out);
}

// Round 4
// 116.620 us; speedup vs baseline: 1.8045x; 1.8045x over previous
//
#include <hip/hip_runtime.h>
#include <hip/hip_bf16.h>

// Problem constants (from reference)
#define BATCH   16384
#define C_SEL   32
#define C_TOTAL 64
#define IN_F    128
#define OUT_F   128

#define BM      64    // batch rows per job
#define NGRP    32    // mtile groups (blocks per channel)
#define NJOBS   8     // jobs per block:  NGRP*NJOBS*BM == BATCH

typedef __bf16 bf16x8 __attribute__((ext_vector_type(8)));
typedef float  f32x4  __attribute__((ext_vector_type(4)));

__device__ __forceinline__ bf16x8 cvt_bf16x8(const float4 f0, const float4 f1) {
    bf16x8 a;
    a[0] = (__bf16)f0.x; a[1] = (__bf16)f0.y; a[2] = (__bf16)f0.z; a[3] = (__bf16)f0.w;
    a[4] = (__bf16)f1.x; a[5] = (__bf16)f1.y; a[6] = (__bf16)f1.z; a[7] = (__bf16)f1.w;
    return a;
}

__global__ __launch_bounds__(256, 4) void pl_mfma_kernel(
    const float* __restrict__ inp,       // (BATCH, C_SEL, IN_F)
    const float* __restrict__ weight,    // (C_TOTAL, OUT_F, IN_F)
    const float* __restrict__ bias,      // (C_TOTAL, OUT_F)
    const int*   __restrict__ channels,  // (C_SEL,)
    float*       __restrict__ out)       // (BATCH, C_SEL, OUT_F)
{
    // W[ch] as bf16 [128][128] = 32 KB; bank-conflict-free via 16B-unit XOR swizzle.
    __shared__ __bf16 ldsW[OUT_F * IN_F];

    const int bid = blockIdx.x;          // 1024 blocks
    const int c   = bid & 31;            // channel fastest (XCD x serves c == x mod 8)
    const int g   = bid >> 5;            // mtile group 0..31
    const int ch  = channels[c];

    const int t  = threadIdx.x;
    const int w  = t >> 6;               // wave 0..3 -> rows [w*16, w*16+16)
    const int l  = t & 63;
    const int lr = l & 15;               // fragment row (A) / col (B)
    const int lg = l >> 4;               // k-group 0..3

    // per-lane A base (floats): job j adds j*JSTRIDE
    const size_t JSTRIDE = (size_t)NGRP * BM * C_SEL * IN_F;   // 8,388,608 floats
    const float* abase = inp + (size_t)g * BM * C_SEL * IN_F
                       + ((size_t)(w * 16 + lr) * C_SEL + (size_t)c) * IN_F + lg * 8;

    // ---- prologue: issue job 0 and job 1 A-loads (fire HBM early) ----
    float4 raA[8], raB[8];
    #pragma unroll
    for (int ks = 0; ks < 4; ++ks) {
        raA[2 * ks]     = *reinterpret_cast<const float4*>(abase + ks * 32);
        raA[2 * ks + 1] = *reinterpret_cast<const float4*>(abase + ks * 32 + 4);
    }
    #pragma unroll
    for (int ks = 0; ks < 4; ++ks) {
        raB[2 * ks]     = *reinterpret_cast<const float4*>(abase + JSTRIDE + ks * 32);
        raB[2 * ks + 1] = *reinterpret_cast<const float4*>(abase + JSTRIDE + ks * 32 + 4);
    }

    // ---- stage W[ch] fp32 -> bf16 into LDS once (swizzled 16B units) ----
    const float* wsrc = weight + (size_t)ch * (OUT_F * IN_F);
    #pragma unroll
    for (int i = 0; i < 8; ++i) {
        const int fidx = i * 2048 + t * 8;
        const int row  = fidx >> 7;
        const int u    = (fidx & 127) >> 3;
        const float4 f0 = *reinterpret_cast<const float4*>(wsrc + fidx);
        const float4 f1 = *reinterpret_cast<const float4*>(wsrc + fidx + 4);
        const int up = u ^ (row & 7);
        *reinterpret_cast<bf16x8*>(&ldsW[row * IN_F + up * 8]) = cvt_bf16x8(f0, f1);
    }

    // ---- bias into registers (once) ----
    float bv[8];
    const float* brow = bias + (size_t)ch * OUT_F;
    #pragma unroll
    for (int nt = 0; nt < 8; ++nt) bv[nt] = brow[nt * 16 + lr];

    __syncthreads();

    // per-lane output base (floats): job j adds j*JSTRIDE, row j2 adds j2*4096
    float* obase = out + (size_t)g * BM * C_SEL * OUT_F
                 + ((size_t)(w * 16 + lg * 4) * C_SEL + (size_t)c) * OUT_F + lr;

    // ---- job loop, manually 2x-unrolled so raA/raB indexing stays static ----
    #pragma unroll
    for (int jj = 0; jj < NJOBS; jj += 2) {
        // ===== even job jj (consumes raA) =====
        {
            f32x4 acc[8];
            #pragma unroll
            for (int nt = 0; nt < 8; ++nt) { f32x4 z = {0.f,0.f,0.f,0.f}; acc[nt] = z; }

            #pragma unroll
            for (int ks = 0; ks < 4; ++ks) {
                const bf16x8 a = cvt_bf16x8(raA[2 * ks], raA[2 * ks + 1]);  // vmcnt wait here
                #pragma unroll
                for (int nt = 0; nt < 8; ++nt) {
                    const int row = nt * 16 + lr;
                    const int u   = (ks * 4 + lg) ^ (lr & 7);
                    const bf16x8 b = *reinterpret_cast<const bf16x8*>(&ldsW[row * IN_F + u * 8]);
                    acc[nt] = __builtin_amdgcn_mfma_f32_16x16x32_bf16(a, b, acc[nt], 0, 0, 0);
                }
            }

            // prefetch job jj+2 into raA (raA fully consumed above)
            if (jj + 2 < NJOBS) {
                const float* p = abase + (size_t)(jj + 2) * JSTRIDE;
                #pragma unroll
                for (int ks = 0; ks < 4; ++ks) {
                    raA[2 * ks]     = *reinterpret_cast<const float4*>(p + ks * 32);
                    raA[2 * ks + 1] = *reinterpret_cast<const float4*>(p + ks * 32 + 4);
                }
            }

            float* o = obase + (size_t)jj * JSTRIDE;
            #pragma unroll
            for (int j2 = 0; j2 < 4; ++j2) {
                #pragma unroll
                for (int nt = 0; nt < 8; ++nt) {
                    o[(size_t)j2 * (C_SEL * OUT_F) + nt * 16] = acc[nt][j2] + bv[nt];
                }
            }
        }
        // ===== odd job jj+1 (consumes raB) =====
        {
            f32x4 acc[8];
            #pragma unroll
            for (int nt = 0; nt < 8; ++nt) { f32x4 z = {0.f,0.f,0.f,0.f}; acc[nt] = z; }

            #pragma unroll
            for (int ks = 0; ks < 4; ++ks) {
                const bf16x8 a = cvt_bf16x8(raB[2 * ks], raB[2 * ks + 1]);
                #pragma unroll
                for (int nt = 0; nt < 8; ++nt) {
                    const int row = nt * 16 + lr;
                    const int u   = (ks * 4 + lg) ^ (lr & 7);
                    const bf16x8 b = *reinterpret_cast<const bf16x8*>(&ldsW[row * IN_F + u * 8]);
                    acc[nt] = __builtin_amdgcn_mfma_f32_16x16x32_bf16(a, b, acc[nt], 0, 0, 0);
                }
            }

            if (jj + 3 < NJOBS) {
                const float* p = abase + (size_t)(jj + 3) * JSTRIDE;
                #pragma unroll
                for (int ks = 0; ks < 4; ++ks) {
                    raB[2 * ks]     = *reinterpret_cast<const float4*>(p + ks * 32);
                    raB[2 * ks + 1] = *reinterpret_cast<const float4*>(p + ks * 32 + 4);
                }
            }

            float* o = obase + (size_t)(jj + 1) * JSTRIDE;
            #pragma unroll
            for (int j2 = 0; j2 < 4; ++j2) {
                #pragma unroll
                for (int nt = 0; nt < 8; ++nt) {
                    o[(size_t)j2 * (C_SEL * OUT_F) + nt * 16] = acc[nt][j2] + bv[nt];
                }
            }
        }
    }
}

extern "C" void kernel_launch(void* const* d_in, const int* in_sizes, int n_in,
                              void* d_out, int out_size, void* d_ws, size_t ws_size,
                              hipStream_t stream) {
    const float* inp      = (const float*)d_in[0];
    const float* weight   = (const float*)d_in[1];
    const float* bias     = (const float*)d_in[2];
    const int*   channels = (const int*)d_in[3];
    float*       out      = (float*)d_out;

    dim3 grid(C_SEL * NGRP);   // 1024 blocks, channel-fastest
    dim3 block(256);
    pl_mfma_kernel<<<grid, block, 0, stream>>>(inp, weight, bias, channels, out);
}